// Round 1
// baseline (177.524 us; speedup 1.0000x reference)
//
#include <hip/hip_runtime.h>

#define TT 2048
#define VV 1024
#define BB 8
#define BLOCK 256

// One workgroup per (b, t). Computes logits[b,t,:] via:
//   c = idx[b,t]
//   L(s) = w2*cnt_c(s) + (w0-w2)*[idx[s]==c] + (w1-w2)*[idx[s-1]==c]   (s <= t)
//   logits[v] = sum_{s<=t, idx[s]==v} L(s)
// then softmax over V in LDS and coalesced float4 store.
__global__ __launch_bounds__(BLOCK) void min_model_kernel(
    const int* __restrict__ idx, const float* __restrict__ w,
    float* __restrict__ out)
{
    __shared__ float logits[VV];
    __shared__ int   wsum[4];
    __shared__ float red[4];

    const int bt  = blockIdx.x;
    const int b   = bt >> 11;          // / TT
    const int t   = bt & (TT - 1);     // % TT
    const int tid = threadIdx.x;
    const int lane = tid & 63;
    const int wid  = tid >> 6;

    const int* __restrict__ row = idx + b * TT;
    const int c = row[t];
    const float w0 = w[0], w1 = w[1], w2 = w[2];
    const float dw0 = w0 - w2, dw1 = w1 - w2;

    // zero the logits accumulator (V=1024, 4 per thread)
    #pragma unroll
    for (int i = tid; i < VV; i += BLOCK) logits[i] = 0.0f;
    __syncthreads();

    // scan s = 0..t in chunks of 256, maintaining running count of token c
    int carry = 0;
    const int nchunk = (t >> 8) + 1;
    for (int ch = 0; ch < nchunk; ++ch) {
        const int s = (ch << 8) + tid;
        const bool valid = (s <= t);
        int tok = -1, tokp = -1;
        if (valid) {
            tok = row[s];
            if (s > 0) tokp = row[s - 1];
        }
        const int f  = (tok  == c) ? 1 : 0;
        const int fp = (tokp == c) ? 1 : 0;

        // wave-level inclusive prefix count of f via ballot
        const unsigned long long bal = __ballot(f);
        const int pre = __popcll(bal & ((1ULL << lane) - 1ULL));
        if (lane == 0) wsum[wid] = __popcll(bal);
        __syncthreads();

        int off = carry;
        for (int ww = 0; ww < wid; ++ww) off += wsum[ww];
        const int cnt = off + pre + f;   // inclusive count of c in row[0..s]

        if (valid) {
            const float L = w2 * (float)cnt + dw0 * (float)f + dw1 * (float)fp;
            atomicAdd(&logits[tok], L);
        }
        carry += wsum[0] + wsum[1] + wsum[2] + wsum[3];
        __syncthreads();   // also makes atomics visible before next iter / softmax
    }

    // ---- softmax over V entries (each thread owns 4 contiguous) ----
    const float4 l4 = *(const float4*)&logits[tid << 2];
    float m = fmaxf(fmaxf(l4.x, l4.y), fmaxf(l4.z, l4.w));
    #pragma unroll
    for (int o = 32; o > 0; o >>= 1)
        m = fmaxf(m, __shfl_xor(m, o, 64));
    if (lane == 0) red[wid] = m;
    __syncthreads();
    m = fmaxf(fmaxf(red[0], red[1]), fmaxf(red[2], red[3]));

    const float e0 = expf(l4.x - m), e1 = expf(l4.y - m);
    const float e2 = expf(l4.z - m), e3 = expf(l4.w - m);
    float sm = e0 + e1 + e2 + e3;
    #pragma unroll
    for (int o = 32; o > 0; o >>= 1)
        sm += __shfl_xor(sm, o, 64);
    __syncthreads();                 // all reads of red[] (max) done
    if (lane == 0) red[wid] = sm;
    __syncthreads();
    const float Z   = red[0] + red[1] + red[2] + red[3];
    const float inv = 1.0f / Z;

    const float4 o4 = { e0 * inv, e1 * inv, e2 * inv, e3 * inv };
    float4* __restrict__ outp = (float4*)(out + ((size_t)bt << 10));
    outp[tid] = o4;
}

extern "C" void kernel_launch(void* const* d_in, const int* in_sizes, int n_in,
                              void* d_out, int out_size, void* d_ws, size_t ws_size,
                              hipStream_t stream) {
    const int*   idx = (const int*)d_in[0];
    const float* w   = (const float*)d_in[1];
    float*       out = (float*)d_out;
    min_model_kernel<<<BB * TT, BLOCK, 0, stream>>>(idx, w, out);
}